// Round 1
// baseline (1503.240 us; speedup 1.0000x reference)
//
#include <hip/hip_runtime.h>
#include <hip/hip_bf16.h>
#include <math.h>

// Problem constants (match reference)
#define T_TOK 1024
#define HID   2048
#define NEXP  64
#define IDIM  1024
#define ISH   2048      // IS = I * N_SHARED
#define TOPK  8

typedef float  f32x4  __attribute__((ext_vector_type(4)));
typedef __bf16 bf16x8 __attribute__((ext_vector_type(8)));

#define BM 128
#define BN 128
#define BK 64
#define LDK 72   // padded LDS row stride in bf16 (144B, 16B-aligned, balanced bank quads)

__device__ __forceinline__ bf16x8 cvt8(f32x4 a, f32x4 b) {
  bf16x8 v;
  v[0]=(__bf16)a[0]; v[1]=(__bf16)a[1]; v[2]=(__bf16)a[2]; v[3]=(__bf16)a[3];
  v[4]=(__bf16)b[0]; v[5]=(__bf16)b[1]; v[6]=(__bf16)b[2]; v[7]=(__bf16)b[3];
  return v;
}

// ---------------- init: zero expert counts ----------------
__global__ void init_kernel(int* counts) {
  if (threadIdx.x < NEXP) counts[threadIdx.x] = 0;
}

// ---------------- x (f32) -> x_bf16 ----------------
__global__ void xcast_kernel(const float* __restrict__ x, __bf16* __restrict__ xb) {
  long i = ((long)blockIdx.x * 256 + threadIdx.x) * 8;
  f32x4 a = *(const f32x4*)(x + i);
  f32x4 b = *(const f32x4*)(x + i + 4);
  *(bf16x8*)(xb + i) = cvt8(a, b);
}

// ---------------- router: logits + sigmoid + grouped top-k (f32) ----------------
__global__ __launch_bounds__(256)
void router_kernel(const float* __restrict__ x, const float* __restrict__ gw,
                   const float* __restrict__ eb,
                   int* __restrict__ ids, float* __restrict__ wts,
                   int* __restrict__ counts)
{
  __shared__ __align__(16) float xs[HID];
  __shared__ float red[256];
  __shared__ float sc[NEXP], sb[NEXP];
  const int t = blockIdx.x, tid = threadIdx.x;

  const f32x4* xsrc = (const f32x4*)(x + (long)t * HID);
  f32x4* xd = (f32x4*)xs;
  xd[tid]       = xsrc[tid];
  xd[tid + 256] = xsrc[tid + 256];
  __syncthreads();

  const int e = tid & 63, part = tid >> 6;
  const f32x4* wrow = (const f32x4*)(gw + (long)e * HID + part * 512);
  const f32x4* xrow = (const f32x4*)(xs + part * 512);
  float s = 0.f;
  #pragma unroll 4
  for (int j = 0; j < 128; ++j) {
    f32x4 wv = wrow[j], xv = xrow[j];
    s += wv[0]*xv[0] + wv[1]*xv[1] + wv[2]*xv[2] + wv[3]*xv[3];
  }
  red[tid] = s;
  __syncthreads();
  if (part == 0) {
    float logit = red[e] + red[e+64] + red[e+128] + red[e+192];
    float sig = 1.f / (1.f + expf(-logit));   // accurate exp: selection must match f32 ref
    sc[e] = sig; sb[e] = sig + eb[e];
  }
  __syncthreads();

  if (tid == 0) {
    // group scores = sum of top-2 biased scores per group of 8
    float gsc[8];
    for (int g = 0; g < 8; ++g) {
      float m1 = -1e30f, m2 = -1e30f;
      for (int j = 0; j < 8; ++j) {
        float v = sb[g*8 + j];
        if (v > m1) { m2 = m1; m1 = v; } else if (v > m2) m2 = v;
      }
      gsc[g] = m1 + m2;
    }
    // top-4 groups (ties -> lower index, matches lax.top_k)
    unsigned gmask = 0;
    for (int it = 0; it < 4; ++it) {
      int best = 0; float bv = -1e30f;
      for (int g = 0; g < 8; ++g)
        if (!((gmask >> g) & 1) && gsc[g] > bv) { bv = gsc[g]; best = g; }
      gmask |= 1u << best;
    }
    // top-8 experts among allowed groups by biased score
    unsigned long long taken = 0;
    int id8[8]; float wsum = 0.f;
    for (int it = 0; it < 8; ++it) {
      int best = 0; float bv = -1e30f;
      for (int e2 = 0; e2 < 64; ++e2) {
        if (!((gmask >> (e2 >> 3)) & 1)) continue;
        if ((taken >> e2) & 1) continue;
        float v = sb[e2];
        if (v > bv) { bv = v; best = e2; }
      }
      taken |= 1ull << best;
      id8[it] = best; wsum += sc[best];
    }
    float inv = 2.5f / wsum;   // fold ROUTED_SCALE into weights
    for (int k = 0; k < 8; ++k) {
      ids[t*8 + k] = id8[k];
      wts[t*8 + k] = sc[id8[k]] * inv;
      atomicAdd(&counts[id8[k]], 1);
    }
  }
}

// ---------------- prefix scan over 64 experts ----------------
__global__ void scan_kernel(const int* __restrict__ counts,
                            int* __restrict__ seg_off, int* __restrict__ cursors) {
  if (threadIdx.x == 0) {
    int off = 0;
    for (int e = 0; e < NEXP; ++e) { seg_off[e] = off; cursors[e] = off; off += counts[e]; }
  }
}

// ---------------- scatter (t, w) into per-expert segments ----------------
__global__ void scatter_kernel(const int* __restrict__ ids, const float* __restrict__ wts,
                               int* __restrict__ cursors,
                               int* __restrict__ tok_list, float* __restrict__ wgt_list) {
  int idx = blockIdx.x * 256 + threadIdx.x;
  if (idx >= T_TOK * TOPK) return;
  int t = idx >> 3;
  int e = ids[idx];
  int pos = atomicAdd(&cursors[e], 1);
  tok_list[pos] = t;
  wgt_list[pos] = wts[idx];
}

// ---------------- fused gate/up GEMM + silu*mul -> bf16 H ----------------
// C[m, n] over rows = (gathered) tokens, cols = intermediate dim. K = HID.
// B matrices are f32 [N, K] (B^T layout), converted to bf16 during LDS staging.
__global__ __launch_bounds__(256, 2)
void gateup_kernel(const __bf16* __restrict__ A,      // [T, K] bf16
                   const float*  __restrict__ Bg0,
                   const float*  __restrict__ Bu0,
                   long strideBe, int ldB, int K,
                   __bf16* __restrict__ Hout, int ldh,
                   const int* __restrict__ seg_off,
                   const int* __restrict__ seg_cnt,
                   const int* __restrict__ tok_list,
                   int Mfull)
{
  const int e = blockIdx.z;
  const int mt = blockIdx.y, nt = blockIdx.x;
  const int soff = seg_off ? seg_off[e] : 0;
  const int cnt  = seg_cnt ? seg_cnt[e] : Mfull;
  const int rem  = cnt - mt * BM;
  if (rem <= 0) return;

  const float* Bg = Bg0 + (long)e * strideBe + (long)nt * BN * ldB;
  const float* Bu = Bu0 + (long)e * strideBe + (long)nt * BN * ldB;

  __shared__ __align__(16) __bf16 As [BM * LDK];
  __shared__ __align__(16) __bf16 Bgs[BN * LDK];
  __shared__ __align__(16) __bf16 Bus[BN * LDK];

  const int tid = threadIdx.x;
  const int lane = tid & 63;
  const int w = tid >> 6;
  const int wm = (w >> 1) * 64, wn = (w & 1) * 64;

  // per-thread A staging chunks (4 chunks of 8 bf16)
  const __bf16* aptr[4];
  int arow[4], akc[4];
  #pragma unroll
  for (int i = 0; i < 4; ++i) {
    int c = tid + i * 256;
    int r = c >> 3;
    arow[i] = r; akc[i] = c & 7;
    int rr = (r < rem) ? r : (rem - 1);
    int rg = tok_list ? tok_list[soff + mt * BM + rr] : (mt * BM + rr);
    aptr[i] = A + (long)rg * K + akc[i] * 8;
  }

  f32x4 accg[4][4] = {}, accu[4][4] = {};

  for (int k0 = 0; k0 < K; k0 += BK) {
    __syncthreads();
    #pragma unroll
    for (int i = 0; i < 4; ++i) {
      bf16x8 v = *(const bf16x8*)(aptr[i] + k0);
      *(bf16x8*)&As[arow[i] * LDK + akc[i] * 8] = v;
    }
    #pragma unroll
    for (int i = 0; i < 4; ++i) {
      int c = tid + i * 256;
      int r = c >> 3, kc = c & 7;
      const float* sg = Bg + (long)r * ldB + k0 + kc * 8;
      f32x4 a0 = *(const f32x4*)sg;
      f32x4 a1 = *(const f32x4*)(sg + 4);
      *(bf16x8*)&Bgs[r * LDK + kc * 8] = cvt8(a0, a1);
      const float* su = Bu + (long)r * ldB + k0 + kc * 8;
      f32x4 b0 = *(const f32x4*)su;
      f32x4 b1 = *(const f32x4*)(su + 4);
      *(bf16x8*)&Bus[r * LDK + kc * 8] = cvt8(b0, b1);
    }
    __syncthreads();
    #pragma unroll
    for (int kh = 0; kh < 2; ++kh) {
      const int ko = kh * 32 + (lane >> 4) * 8;
      bf16x8 af[4], bgf[4], buf_[4];
      #pragma unroll
      for (int m = 0; m < 4; ++m) af[m]  = *(const bf16x8*)&As [(wm + m*16 + (lane & 15)) * LDK + ko];
      #pragma unroll
      for (int n = 0; n < 4; ++n) bgf[n] = *(const bf16x8*)&Bgs[(wn + n*16 + (lane & 15)) * LDK + ko];
      #pragma unroll
      for (int n = 0; n < 4; ++n) buf_[n]= *(const bf16x8*)&Bus[(wn + n*16 + (lane & 15)) * LDK + ko];
      #pragma unroll
      for (int m = 0; m < 4; ++m)
        #pragma unroll
        for (int n = 0; n < 4; ++n) {
          accg[m][n] = __builtin_amdgcn_mfma_f32_16x16x32_bf16(af[m], bgf[n], accg[m][n], 0, 0, 0);
          accu[m][n] = __builtin_amdgcn_mfma_f32_16x16x32_bf16(af[m], buf_[n], accu[m][n], 0, 0, 0);
        }
    }
  }

  const long hbase = (long)(soff + mt * BM);
  #pragma unroll
  for (int m = 0; m < 4; ++m) {
    #pragma unroll
    for (int n = 0; n < 4; ++n) {
      const int col = nt * BN + wn + n * 16 + (lane & 15);
      #pragma unroll
      for (int r = 0; r < 4; ++r) {
        const int rl = wm + m * 16 + (lane >> 4) * 4 + r;
        if (rl < rem) {
          float g = accg[m][n][r], u = accu[m][n][r];
          float h = g * u / (1.f + __expf(-g));     // silu(g)*u
          Hout[(hbase + rl) * (long)ldh + col] = (__bf16)h;
        }
      }
    }
  }
}

// ---------------- down GEMM: Out[t, :] (+)= w * (H_seg @ Wd^T) ----------------
template<bool ROUTED>
__global__ __launch_bounds__(256, 2)
void down_kernel(const __bf16* __restrict__ A,   // [rows, K] bf16, seg-ordered
                 const float*  __restrict__ B0,  // [N, K] f32 per expert
                 long strideBe, int ldB, int K,
                 float* __restrict__ Out,
                 const int* __restrict__ seg_off,
                 const int* __restrict__ seg_cnt,
                 const int* __restrict__ tok_list,
                 const float* __restrict__ wgt_list,
                 int Mfull)
{
  const int e = blockIdx.z, mt = blockIdx.y, nt = blockIdx.x;
  const int soff = ROUTED ? seg_off[e] : 0;
  const int cnt  = ROUTED ? seg_cnt[e] : Mfull;
  const int rem  = cnt - mt * BM;
  if (rem <= 0) return;

  const float* B = B0 + (long)e * strideBe + (long)nt * BN * ldB;
  __shared__ __align__(16) __bf16 As[BM * LDK];
  __shared__ __align__(16) __bf16 Bs[BN * LDK];

  const int tid = threadIdx.x;
  const int lane = tid & 63;
  const int w = tid >> 6;
  const int wm = (w >> 1) * 64, wn = (w & 1) * 64;

  const __bf16* aptr[4];
  int arow[4], akc[4];
  #pragma unroll
  for (int i = 0; i < 4; ++i) {
    int c = tid + i * 256;
    int r = c >> 3;
    arow[i] = r; akc[i] = c & 7;
    int rr = (r < rem) ? r : (rem - 1);
    aptr[i] = A + (long)(soff + mt * BM + rr) * K + akc[i] * 8;
  }

  f32x4 acc[4][4] = {};

  for (int k0 = 0; k0 < K; k0 += BK) {
    __syncthreads();
    #pragma unroll
    for (int i = 0; i < 4; ++i) {
      bf16x8 v = *(const bf16x8*)(aptr[i] + k0);
      *(bf16x8*)&As[arow[i] * LDK + akc[i] * 8] = v;
    }
    #pragma unroll
    for (int i = 0; i < 4; ++i) {
      int c = tid + i * 256;
      int r = c >> 3, kc = c & 7;
      const float* sb_ = B + (long)r * ldB + k0 + kc * 8;
      f32x4 a0 = *(const f32x4*)sb_;
      f32x4 a1 = *(const f32x4*)(sb_ + 4);
      *(bf16x8*)&Bs[r * LDK + kc * 8] = cvt8(a0, a1);
    }
    __syncthreads();
    #pragma unroll
    for (int kh = 0; kh < 2; ++kh) {
      const int ko = kh * 32 + (lane >> 4) * 8;
      bf16x8 af[4], bf_[4];
      #pragma unroll
      for (int m = 0; m < 4; ++m) af[m] = *(const bf16x8*)&As[(wm + m*16 + (lane & 15)) * LDK + ko];
      #pragma unroll
      for (int n = 0; n < 4; ++n) bf_[n]= *(const bf16x8*)&Bs[(wn + n*16 + (lane & 15)) * LDK + ko];
      #pragma unroll
      for (int m = 0; m < 4; ++m)
        #pragma unroll
        for (int n = 0; n < 4; ++n)
          acc[m][n] = __builtin_amdgcn_mfma_f32_16x16x32_bf16(af[m], bf_[n], acc[m][n], 0, 0, 0);
    }
  }

  #pragma unroll
  for (int m = 0; m < 4; ++m) {
    #pragma unroll
    for (int n = 0; n < 4; ++n) {
      const int col = nt * BN + wn + n * 16 + (lane & 15);
      #pragma unroll
      for (int r = 0; r < 4; ++r) {
        const int rl = wm + m * 16 + (lane >> 4) * 4 + r;
        if (rl < rem) {
          float v = acc[m][n][r];
          if (ROUTED) {
            int srow = soff + mt * BM + rl;
            atomicAdd(&Out[(long)tok_list[srow] * HID + col], v * wgt_list[srow]);
          } else {
            Out[(long)(mt * BM + rl) * HID + col] = v;
          }
        }
      }
    }
  }
}

// ---------------- launch ----------------
extern "C" void kernel_launch(void* const* d_in, const int* in_sizes, int n_in,
                              void* d_out, int out_size, void* d_ws, size_t ws_size,
                              hipStream_t stream) {
  const float* x      = (const float*)d_in[0];
  const float* gate_w = (const float*)d_in[1];
  const float* e_bias = (const float*)d_in[2];
  const float* w_gate = (const float*)d_in[3];
  const float* w_up   = (const float*)d_in[4];
  const float* w_down = (const float*)d_in[5];
  const float* sw_gu  = (const float*)d_in[6];
  const float* sw_d   = (const float*)d_in[7];
  float* out = (float*)d_out;
  char* ws = (char*)d_ws;

  size_t off = 0;
  __bf16* x_bf = (__bf16*)(ws + off);        off += (size_t)T_TOK * HID * 2;   // 4 MB
  int*    ids  = (int*)(ws + off);           off += T_TOK * TOPK * 4;
  float*  wts  = (float*)(ws + off);         off += T_TOK * TOPK * 4;
  int* counts  = (int*)(ws + off);           off += 256;
  int* segoff  = (int*)(ws + off);           off += 256;
  int* cursors = (int*)(ws + off);           off += 256;
  int* tok_list = (int*)(ws + off);          off += T_TOK * TOPK * 4;
  float* wgt_list = (float*)(ws + off);      off += T_TOK * TOPK * 4;
  off = (off + 255) & ~(size_t)255;
  __bf16* h_buf  = (__bf16*)(ws + off);      off += (size_t)T_TOK * TOPK * IDIM * 2; // 16 MB
  __bf16* hs_buf = (__bf16*)(ws + off);      off += (size_t)T_TOK * ISH * 2;         // 4 MB

  init_kernel<<<1, 64, 0, stream>>>(counts);
  xcast_kernel<<<(T_TOK * HID) / (256 * 8), 256, 0, stream>>>(x, x_bf);
  router_kernel<<<T_TOK, 256, 0, stream>>>(x, gate_w, e_bias, ids, wts, counts);
  scan_kernel<<<1, 64, 0, stream>>>(counts, segoff, cursors);
  scatter_kernel<<<(T_TOK * TOPK + 255) / 256, 256, 0, stream>>>(ids, wts, cursors, tok_list, wgt_list);

  // routed gate/up: M=seg, N=IDIM, K=HID
  gateup_kernel<<<dim3(IDIM / BN, 8, NEXP), 256, 0, stream>>>(
      x_bf, w_gate, w_up, (long)IDIM * HID, HID, HID,
      h_buf, IDIM, segoff, counts, tok_list, 0);

  // shared gate/up: M=T, N=ISH, K=HID
  gateup_kernel<<<dim3(ISH / BN, T_TOK / BM, 1), 256, 0, stream>>>(
      x_bf, sw_gu, sw_gu + (size_t)ISH * HID, 0, HID, HID,
      hs_buf, ISH, nullptr, nullptr, nullptr, T_TOK);

  // shared down: writes out (initializes all of d_out)
  down_kernel<false><<<dim3(HID / BN, T_TOK / BM, 1), 256, 0, stream>>>(
      hs_buf, sw_d, 0, ISH, ISH, out, nullptr, nullptr, nullptr, nullptr, T_TOK);

  // routed down: atomic accumulate (weights include ROUTED_SCALE)
  down_kernel<true><<<dim3(HID / BN, 8, NEXP), 256, 0, stream>>>(
      h_buf, w_down, (long)HID * IDIM, IDIM, IDIM, out, segoff, counts, tok_list, wgt_list, 0);
}

// Round 2
// 729.177 us; speedup vs baseline: 2.0616x; 2.0616x over previous
//
#include <hip/hip_runtime.h>
#include <hip/hip_bf16.h>
#include <math.h>

// Problem constants (match reference)
#define T_TOK 1024
#define HID   2048
#define NEXP  64
#define IDIM  1024
#define ISH   2048      // IS = I * N_SHARED
#define TOPK  8

typedef float  f32x4  __attribute__((ext_vector_type(4)));
typedef __bf16 bf16x8 __attribute__((ext_vector_type(8)));

#define BM  128
#define BN_ 64
#define BK  64

__device__ __forceinline__ bf16x8 cvt8(f32x4 a, f32x4 b) {
  bf16x8 v;
  v[0]=(__bf16)a[0]; v[1]=(__bf16)a[1]; v[2]=(__bf16)a[2]; v[3]=(__bf16)a[3];
  v[4]=(__bf16)b[0]; v[5]=(__bf16)b[1]; v[6]=(__bf16)b[2]; v[7]=(__bf16)b[3];
  return v;
}

// ---------------- init: zero expert counts ----------------
__global__ void init_kernel(int* counts) {
  if (threadIdx.x < NEXP) counts[threadIdx.x] = 0;
}

// ---------------- x (f32) -> x_bf16 ----------------
__global__ void xcast_kernel(const float* __restrict__ x, __bf16* __restrict__ xb) {
  long i = ((long)blockIdx.x * 256 + threadIdx.x) * 8;
  f32x4 a = *(const f32x4*)(x + i);
  f32x4 b = *(const f32x4*)(x + i + 4);
  *(bf16x8*)(xb + i) = cvt8(a, b);
}

// ---------------- router: logits + sigmoid + grouped top-k (f32) ----------------
__global__ __launch_bounds__(256)
void router_kernel(const float* __restrict__ x, const float* __restrict__ gw,
                   const float* __restrict__ eb,
                   int* __restrict__ ids, float* __restrict__ wts,
                   int* __restrict__ counts)
{
  __shared__ __align__(16) float xs[HID];
  __shared__ float red[256];
  __shared__ float sc[NEXP], sb[NEXP];
  const int t = blockIdx.x, tid = threadIdx.x;

  const f32x4* xsrc = (const f32x4*)(x + (long)t * HID);
  f32x4* xd = (f32x4*)xs;
  xd[tid]       = xsrc[tid];
  xd[tid + 256] = xsrc[tid + 256];
  __syncthreads();

  const int e = tid & 63, part = tid >> 6;
  const f32x4* wrow = (const f32x4*)(gw + (long)e * HID + part * 512);
  const f32x4* xrow = (const f32x4*)(xs + part * 512);
  float s = 0.f;
  #pragma unroll 4
  for (int j = 0; j < 128; ++j) {
    f32x4 wv = wrow[j], xv = xrow[j];
    s += wv[0]*xv[0] + wv[1]*xv[1] + wv[2]*xv[2] + wv[3]*xv[3];
  }
  red[tid] = s;
  __syncthreads();
  if (part == 0) {
    float logit = red[e] + red[e+64] + red[e+128] + red[e+192];
    float sig = 1.f / (1.f + expf(-logit));   // accurate exp: selection must match f32 ref
    sc[e] = sig; sb[e] = sig + eb[e];
  }
  __syncthreads();

  if (tid == 0) {
    float gsc[8];
    for (int g = 0; g < 8; ++g) {
      float m1 = -1e30f, m2 = -1e30f;
      for (int j = 0; j < 8; ++j) {
        float v = sb[g*8 + j];
        if (v > m1) { m2 = m1; m1 = v; } else if (v > m2) m2 = v;
      }
      gsc[g] = m1 + m2;
    }
    unsigned gmask = 0;
    for (int it = 0; it < 4; ++it) {
      int best = 0; float bv = -1e30f;
      for (int g = 0; g < 8; ++g)
        if (!((gmask >> g) & 1) && gsc[g] > bv) { bv = gsc[g]; best = g; }
      gmask |= 1u << best;
    }
    unsigned long long taken = 0;
    int id8[8]; float wsum = 0.f;
    for (int it = 0; it < 8; ++it) {
      int best = 0; float bv = -1e30f;
      for (int e2 = 0; e2 < 64; ++e2) {
        if (!((gmask >> (e2 >> 3)) & 1)) continue;
        if ((taken >> e2) & 1) continue;
        float v = sb[e2];
        if (v > bv) { bv = v; best = e2; }
      }
      taken |= 1ull << best;
      id8[it] = best; wsum += sc[best];
    }
    float inv = 2.5f / wsum;   // fold ROUTED_SCALE into weights
    for (int k = 0; k < 8; ++k) {
      ids[t*8 + k] = id8[k];
      wts[t*8 + k] = sc[id8[k]] * inv;
      atomicAdd(&counts[id8[k]], 1);
    }
  }
}

// ---------------- prefix scan + (expert, mt) pair worklist ----------------
__global__ void scan_kernel(const int* __restrict__ counts,
                            int* __restrict__ seg_off, int* __restrict__ cursors,
                            int* __restrict__ pair_e, int* __restrict__ pair_mt,
                            int* __restrict__ npairs) {
  if (threadIdx.x == 0) {
    int off = 0, np = 0;
    for (int e = 0; e < NEXP; ++e) {
      seg_off[e] = off; cursors[e] = off;
      int c = counts[e]; off += c;
      for (int m = 0; m * BM < c; ++m) { pair_e[np] = e; pair_mt[np] = m; ++np; }
    }
    npairs[0] = np;
  }
}

// ---------------- scatter (t, w) into per-expert segments ----------------
__global__ void scatter_kernel(const int* __restrict__ ids, const float* __restrict__ wts,
                               int* __restrict__ cursors,
                               int* __restrict__ tok_list, float* __restrict__ wgt_list) {
  int idx = blockIdx.x * 256 + threadIdx.x;
  if (idx >= T_TOK * TOPK) return;
  int t = idx >> 3;
  int e = ids[idx];
  int pos = atomicAdd(&cursors[e], 1);
  tok_list[pos] = t;
  wgt_list[pos] = wts[idx];
}

// ---------------- streaming GEMM: C = A(bf16, maybe gathered) x B(f32 [N,K])^T ----
// B is streamed per-wave global->reg->bf16 frag (no LDS, no barrier on the big
// stream). A is double-buffered in swizzled LDS, reg-prefetched 1 step ahead;
// ONE barrier per K-step. Wave w owns cols [w*16, w*16+16) of the 64-col tile.
// EPI: 0 = bf16 store to C (gate/up), 1 = f32 atomicAdd via tok_list (routed
// down, weight pre-folded into A), 2 = plain f32 store (shared down).
template<int EPI, bool ROUTED>
__global__ __launch_bounds__(256, 3)
void gemm_stream(const __bf16* __restrict__ A, const float* __restrict__ B0,
                 long strideBe, int ldB, int K,
                 void* __restrict__ Cout, int ldc,
                 const int* __restrict__ pair_e, const int* __restrict__ pair_mt,
                 const int* __restrict__ npairs,
                 const int* __restrict__ seg_off, const int* __restrict__ seg_cnt,
                 const int* __restrict__ tok_list,
                 int Mfull)
{
  const int tid  = threadIdx.x;
  const int lane = tid & 63;
  const int wv   = tid >> 6;

  int e, mt0, soff, cnt;
  if (ROUTED) {
    int p = blockIdx.y;
    if (p >= npairs[0]) return;
    e = pair_e[p]; mt0 = pair_mt[p]; soff = seg_off[e]; cnt = seg_cnt[e];
  } else {
    e = 0; mt0 = blockIdx.y; soff = 0; cnt = Mfull;
  }
  const int rem = cnt - mt0 * BM;
  if (rem <= 0) return;

  // per-lane B row pointer: col = nt*64 + wv*16 + (lane&15), k-base (lane>>4)*8
  const float* Bp = B0 + (long)e * strideBe
                  + (long)(blockIdx.x * BN_ + wv * 16 + (lane & 15)) * ldB
                  + ((lane >> 4) * 8);

  __shared__ __align__(16) __bf16 Abuf[2][BM * BK];   // 16 KB each, XOR-swizzled

  // A staging: 4 chunks of bf16x8 per thread per K-step
  const __bf16* aptr[4];
  int aoff[4];
  #pragma unroll
  for (int i = 0; i < 4; ++i) {
    int c = tid + i * 256, r = c >> 3, s = c & 7;
    int rr = (r < rem) ? r : (rem - 1);
    int base = soff + mt0 * BM + rr;
    int arow = (EPI == 0 && ROUTED) ? tok_list[base] : base;
    aptr[i] = A + (long)arow * K + s * 8;
    aoff[i] = r * 64 + ((s ^ (r & 7)) * 8);           // swizzle: slot ^= row&7
  }

  f32x4 acc[8] = {};
  bf16x8 aR[4];
  f32x4 bA[4], bB[4];

#define LOAD_A(k) { _Pragma("unroll") \
  for (int i = 0; i < 4; ++i) aR[i] = *(const bf16x8*)(aptr[i] + (k)); }
#define STORE_A(b) { _Pragma("unroll") \
  for (int i = 0; i < 4; ++i) *(bf16x8*)&Abuf[b][aoff[i]] = aR[i]; }
#define LOAD_B(dst, k) { \
  dst[0] = *(const f32x4*)(Bp + (k));      dst[1] = *(const f32x4*)(Bp + (k) + 4); \
  dst[2] = *(const f32x4*)(Bp + (k) + 32); dst[3] = *(const f32x4*)(Bp + (k) + 36); }
#define COMPUTE(bsrc, b) { _Pragma("unroll") \
  for (int ch = 0; ch < 2; ++ch) { \
    bf16x8 bfrag = cvt8(bsrc[ch*2], bsrc[ch*2+1]); \
    const int ro = ((lane & 15) * 64) + ((((ch*4) + (lane >> 4)) ^ (lane & 7)) * 8); \
    _Pragma("unroll") \
    for (int m = 0; m < 8; ++m) { \
      bf16x8 af = *(const bf16x8*)&Abuf[b][m * 1024 + ro]; \
      acc[m] = __builtin_amdgcn_mfma_f32_16x16x32_bf16(af, bfrag, acc[m], 0, 0, 0); \
    } \
  } }

  LOAD_A(0);
  LOAD_B(bA, 0);
  const int NT = K / BK;                   // even (16 or 32) for all our shapes
  for (int t = 0; t < NT; t += 2) {
    const int k1 = (t + 1 < NT) ? (t + 1) * BK : 0;
    const int k2 = (t + 2 < NT) ? (t + 2) * BK : 0;
    STORE_A(0);
    LOAD_A(k1); LOAD_B(bB, k1);            // in flight across COMPUTE below
    __syncthreads();
    COMPUTE(bA, 0);
    STORE_A(1);
    LOAD_A(k2); LOAD_B(bA, k2);
    __syncthreads();
    COMPUTE(bB, 1);
  }
#undef LOAD_A
#undef STORE_A
#undef LOAD_B
#undef COMPUTE

  if (EPI == 0) {
    // LDS transpose for coalesced bf16x8 stores
    __syncthreads();
    __bf16* Cs = &Abuf[0][0];
    #pragma unroll
    for (int m = 0; m < 8; ++m) {
      #pragma unroll
      for (int r = 0; r < 4; ++r) {
        int row = m * 16 + (lane >> 4) * 4 + r;
        Cs[row * 64 + wv * 16 + (lane & 15)] = (__bf16)acc[m][r];
      }
    }
    __syncthreads();
    __bf16* Cb = (__bf16*)Cout;
    #pragma unroll
    for (int p = 0; p < 4; ++p) {
      int row = p * 32 + (tid >> 3);
      if (row < rem)
        *(bf16x8*)(Cb + (long)(soff + mt0 * BM + row) * ldc + blockIdx.x * BN_ + (tid & 7) * 8) =
            *(const bf16x8*)&Cs[row * 64 + (tid & 7) * 8];
    }
  } else {
    float* Of = (float*)Cout;
    const int col = blockIdx.x * BN_ + wv * 16 + (lane & 15);
    #pragma unroll
    for (int m = 0; m < 8; ++m) {
      #pragma unroll
      for (int r = 0; r < 4; ++r) {
        int row = m * 16 + (lane >> 4) * 4 + r;
        if (row < rem) {
          if (EPI == 1) {
            int orow = tok_list[soff + mt0 * BM + row];
            atomicAdd(Of + (long)orow * HID + col, acc[m][r]);
          } else {
            Of[(long)(mt0 * BM + row) * HID + col] = acc[m][r];
          }
        }
      }
    }
  }
}

// ---------------- fuse: h = silu(g) * u * w  (in place into g) ----------------
__global__ void fuse_kernel(__bf16* __restrict__ g, const __bf16* __restrict__ u,
                            const float* __restrict__ wrow, int rshift) {
  long idx = ((long)blockIdx.x * 256 + threadIdx.x) * 8;
  bf16x8 gv = *(bf16x8*)(g + idx);
  bf16x8 uv = *(const bf16x8*)(u + idx);
  float w = wrow ? wrow[idx >> rshift] : 1.f;
  bf16x8 h;
  #pragma unroll
  for (int j = 0; j < 8; ++j) {
    float gf = (float)gv[j], uf = (float)uv[j];
    h[j] = (__bf16)(w * gf * uf / (1.f + __expf(-gf)));
  }
  *(bf16x8*)(g + idx) = h;
}

// ---------------- launch ----------------
extern "C" void kernel_launch(void* const* d_in, const int* in_sizes, int n_in,
                              void* d_out, int out_size, void* d_ws, size_t ws_size,
                              hipStream_t stream) {
  const float* x      = (const float*)d_in[0];
  const float* gate_w = (const float*)d_in[1];
  const float* e_bias = (const float*)d_in[2];
  const float* w_gate = (const float*)d_in[3];
  const float* w_up   = (const float*)d_in[4];
  const float* w_down = (const float*)d_in[5];
  const float* sw_gu  = (const float*)d_in[6];
  const float* sw_d   = (const float*)d_in[7];
  float* out = (float*)d_out;
  char* ws = (char*)d_ws;

  size_t off = 0;
  __bf16* x_bf = (__bf16*)(ws + off);        off += (size_t)T_TOK * HID * 2;   // 4 MB
  int*    ids  = (int*)(ws + off);           off += T_TOK * TOPK * 4;
  float*  wts  = (float*)(ws + off);         off += T_TOK * TOPK * 4;
  int* counts  = (int*)(ws + off);           off += 256;
  int* segoff  = (int*)(ws + off);           off += 256;
  int* cursors = (int*)(ws + off);           off += 256;
  int* pair_e  = (int*)(ws + off);           off += 1024;
  int* pair_mt = (int*)(ws + off);           off += 1024;
  int* npairs  = (int*)(ws + off);           off += 256;
  int* tok_list = (int*)(ws + off);          off += T_TOK * TOPK * 4;
  float* wgt_list = (float*)(ws + off);      off += T_TOK * TOPK * 4;
  off = (off + 255) & ~(size_t)255;
  __bf16* g_buf = (__bf16*)(ws + off);       off += (size_t)T_TOK * TOPK * IDIM * 2; // 16 MB
  __bf16* u_buf = (__bf16*)(ws + off);       off += (size_t)T_TOK * TOPK * IDIM * 2; // 16 MB
  __bf16* gs_buf = (__bf16*)(ws + off);      off += (size_t)T_TOK * ISH * 2;         // 4 MB
  __bf16* us_buf = (__bf16*)(ws + off);      off += (size_t)T_TOK * ISH * 2;         // 4 MB

  init_kernel<<<1, 64, 0, stream>>>(counts);
  xcast_kernel<<<(T_TOK * HID) / (256 * 8), 256, 0, stream>>>(x, x_bf);
  router_kernel<<<T_TOK, 256, 0, stream>>>(x, gate_w, e_bias, ids, wts, counts);
  scan_kernel<<<1, 64, 0, stream>>>(counts, segoff, cursors, pair_e, pair_mt, npairs);
  scatter_kernel<<<(T_TOK * TOPK + 255) / 256, 256, 0, stream>>>(ids, wts, cursors, tok_list, wgt_list);

  // routed gate & up (separate streams through the same kernel)
  gemm_stream<0, true><<<dim3(IDIM / BN_, 128), 256, 0, stream>>>(
      x_bf, w_gate, (long)IDIM * HID, HID, HID, g_buf, IDIM,
      pair_e, pair_mt, npairs, segoff, counts, tok_list, 0);
  gemm_stream<0, true><<<dim3(IDIM / BN_, 128), 256, 0, stream>>>(
      x_bf, w_up, (long)IDIM * HID, HID, HID, u_buf, IDIM,
      pair_e, pair_mt, npairs, segoff, counts, tok_list, 0);
  // h = silu(g)*u*w  (w includes ROUTED_SCALE and renorm)
  fuse_kernel<<<(T_TOK * TOPK * IDIM) / (256 * 8), 256, 0, stream>>>(g_buf, u_buf, wgt_list, 10);

  // shared gate & up
  gemm_stream<0, false><<<dim3(ISH / BN_, T_TOK / BM), 256, 0, stream>>>(
      x_bf, sw_gu, 0, HID, HID, gs_buf, ISH,
      nullptr, nullptr, nullptr, nullptr, nullptr, nullptr, T_TOK);
  gemm_stream<0, false><<<dim3(ISH / BN_, T_TOK / BM), 256, 0, stream>>>(
      x_bf, sw_gu + (size_t)ISH * HID, 0, HID, HID, us_buf, ISH,
      nullptr, nullptr, nullptr, nullptr, nullptr, nullptr, T_TOK);
  fuse_kernel<<<(T_TOK * ISH) / (256 * 8), 256, 0, stream>>>(gs_buf, us_buf, nullptr, 11);

  // shared down: plain stores (initializes all of d_out)
  gemm_stream<2, false><<<dim3(HID / BN_, T_TOK / BM), 256, 0, stream>>>(
      gs_buf, sw_d, 0, ISH, ISH, out, HID,
      nullptr, nullptr, nullptr, nullptr, nullptr, nullptr, T_TOK);

  // routed down: atomic accumulate (weight already folded into h)
  gemm_stream<1, true><<<dim3(HID / BN_, 128), 256, 0, stream>>>(
      g_buf, w_down, (long)HID * IDIM, IDIM, IDIM, out, HID,
      pair_e, pair_mt, npairs, segoff, counts, tok_list, 0);
}

// Round 3
// 722.202 us; speedup vs baseline: 2.0815x; 1.0097x over previous
//
#include <hip/hip_runtime.h>
#include <hip/hip_bf16.h>
#include <math.h>

// Problem constants (match reference)
#define T_TOK 1024
#define HID   2048
#define NEXP  64
#define IDIM  1024
#define ISH   2048      // IS = I * N_SHARED
#define TOPK  8

typedef float  f32x4  __attribute__((ext_vector_type(4)));
typedef __bf16 bf16x8 __attribute__((ext_vector_type(8)));

#define BM  128
#define BN_ 64
#define BK  64

// Barrier that does NOT drain vmcnt: only waits own DS ops (reads+writes),
// then s_barrier. Global loads stay in flight across it (counted vmcnt waits
// are inserted by the compiler only where their data is consumed).
#define BARRIER_NODRAIN() asm volatile("s_waitcnt lgkmcnt(0)\n\ts_barrier" ::: "memory")

__device__ __forceinline__ bf16x8 cvt8(f32x4 a, f32x4 b) {
  bf16x8 v;
  v[0]=(__bf16)a[0]; v[1]=(__bf16)a[1]; v[2]=(__bf16)a[2]; v[3]=(__bf16)a[3];
  v[4]=(__bf16)b[0]; v[5]=(__bf16)b[1]; v[6]=(__bf16)b[2]; v[7]=(__bf16)b[3];
  return v;
}

// ---------------- init: zero expert counts ----------------
__global__ void init_kernel(int* counts) {
  if (threadIdx.x < NEXP) counts[threadIdx.x] = 0;
}

// ---------------- x (f32) -> x_bf16 ----------------
__global__ void xcast_kernel(const float* __restrict__ x, __bf16* __restrict__ xb) {
  long i = ((long)blockIdx.x * 256 + threadIdx.x) * 8;
  f32x4 a = *(const f32x4*)(x + i);
  f32x4 b = *(const f32x4*)(x + i + 4);
  *(bf16x8*)(xb + i) = cvt8(a, b);
}

// ---------------- router: logits + sigmoid + grouped top-k (f32) ----------------
__global__ __launch_bounds__(256)
void router_kernel(const float* __restrict__ x, const float* __restrict__ gw,
                   const float* __restrict__ eb,
                   int* __restrict__ ids, float* __restrict__ wts,
                   int* __restrict__ counts)
{
  __shared__ __align__(16) float xs[HID];
  __shared__ float red[256];
  __shared__ float sc[NEXP], sb[NEXP];
  const int t = blockIdx.x, tid = threadIdx.x;

  const f32x4* xsrc = (const f32x4*)(x + (long)t * HID);
  f32x4* xd = (f32x4*)xs;
  xd[tid]       = xsrc[tid];
  xd[tid + 256] = xsrc[tid + 256];
  __syncthreads();

  const int e = tid & 63, part = tid >> 6;
  const f32x4* wrow = (const f32x4*)(gw + (long)e * HID + part * 512);
  const f32x4* xrow = (const f32x4*)(xs + part * 512);
  float s = 0.f;
  #pragma unroll 4
  for (int j = 0; j < 128; ++j) {
    f32x4 wv = wrow[j], xv = xrow[j];
    s += wv[0]*xv[0] + wv[1]*xv[1] + wv[2]*xv[2] + wv[3]*xv[3];
  }
  red[tid] = s;
  __syncthreads();
  if (part == 0) {
    float logit = red[e] + red[e+64] + red[e+128] + red[e+192];
    float sig = 1.f / (1.f + expf(-logit));   // accurate exp: selection must match f32 ref
    sc[e] = sig; sb[e] = sig + eb[e];
  }
  __syncthreads();

  if (tid == 0) {
    float gsc[8];
    for (int g = 0; g < 8; ++g) {
      float m1 = -1e30f, m2 = -1e30f;
      for (int j = 0; j < 8; ++j) {
        float v = sb[g*8 + j];
        if (v > m1) { m2 = m1; m1 = v; } else if (v > m2) m2 = v;
      }
      gsc[g] = m1 + m2;
    }
    unsigned gmask = 0;
    for (int it = 0; it < 4; ++it) {
      int best = 0; float bv = -1e30f;
      for (int g = 0; g < 8; ++g)
        if (!((gmask >> g) & 1) && gsc[g] > bv) { bv = gsc[g]; best = g; }
      gmask |= 1u << best;
    }
    unsigned long long taken = 0;
    int id8[8]; float wsum = 0.f;
    for (int it = 0; it < 8; ++it) {
      int best = 0; float bv = -1e30f;
      for (int e2 = 0; e2 < 64; ++e2) {
        if (!((gmask >> (e2 >> 3)) & 1)) continue;
        if ((taken >> e2) & 1) continue;
        float v = sb[e2];
        if (v > bv) { bv = v; best = e2; }
      }
      taken |= 1ull << best;
      id8[it] = best; wsum += sc[best];
    }
    float inv = 2.5f / wsum;   // fold ROUTED_SCALE into weights
    for (int k = 0; k < 8; ++k) {
      ids[t*8 + k] = id8[k];
      wts[t*8 + k] = sc[id8[k]] * inv;
      atomicAdd(&counts[id8[k]], 1);
    }
  }
}

// ---------------- prefix scan + (expert, mt) pair worklist ----------------
__global__ void scan_kernel(const int* __restrict__ counts,
                            int* __restrict__ seg_off, int* __restrict__ cursors,
                            int* __restrict__ pair_e, int* __restrict__ pair_mt,
                            int* __restrict__ npairs) {
  if (threadIdx.x == 0) {
    int off = 0, np = 0;
    for (int e = 0; e < NEXP; ++e) {
      seg_off[e] = off; cursors[e] = off;
      int c = counts[e]; off += c;
      for (int m = 0; m * BM < c; ++m) { pair_e[np] = e; pair_mt[np] = m; ++np; }
    }
    npairs[0] = np;
  }
}

// ---------------- scatter (t, w) into per-expert segments ----------------
__global__ void scatter_kernel(const int* __restrict__ ids, const float* __restrict__ wts,
                               int* __restrict__ cursors,
                               int* __restrict__ tok_list, float* __restrict__ wgt_list) {
  int idx = blockIdx.x * 256 + threadIdx.x;
  if (idx >= T_TOK * TOPK) return;
  int t = idx >> 3;
  int e = ids[idx];
  int pos = atomicAdd(&cursors[e], 1);
  tok_list[pos] = t;
  wgt_list[pos] = wts[idx];
}

// ---------------- streaming GEMM: C = A(bf16, maybe gathered) x B(f32 [N,K])^T ----
// B is streamed per-wave global->reg->bf16 frag (no LDS, no barrier on the big
// stream). A is double-buffered in swizzled LDS, reg-prefetched 1 step ahead;
// ONE no-drain barrier per half K-step, so global loads span barriers.
// Wave w owns cols [w*16, w*16+16) of the 64-col tile.
// EPI: 0 = bf16 store to C (gate/up), 1 = f32 atomicAdd via tok_list (routed
// down, weight pre-folded into A), 2 = plain f32 store (shared down).
template<int EPI, bool ROUTED>
__global__ __launch_bounds__(256, 3)
void gemm_stream(const __bf16* __restrict__ A, const float* __restrict__ B0,
                 long strideBe, int ldB, int K,
                 void* __restrict__ Cout, int ldc,
                 const int* __restrict__ pair_e, const int* __restrict__ pair_mt,
                 const int* __restrict__ npairs,
                 const int* __restrict__ seg_off, const int* __restrict__ seg_cnt,
                 const int* __restrict__ tok_list,
                 int Mfull)
{
  const int tid  = threadIdx.x;
  const int lane = tid & 63;
  const int wv   = tid >> 6;

  int e, mt0, soff, cnt;
  if (ROUTED) {
    int p = blockIdx.y;
    if (p >= npairs[0]) return;
    e = pair_e[p]; mt0 = pair_mt[p]; soff = seg_off[e]; cnt = seg_cnt[e];
  } else {
    e = 0; mt0 = blockIdx.y; soff = 0; cnt = Mfull;
  }
  const int rem = cnt - mt0 * BM;
  if (rem <= 0) return;

  // per-lane B row pointer: col = nt*64 + wv*16 + (lane&15), k-base (lane>>4)*8
  const float* Bp = B0 + (long)e * strideBe
                  + (long)(blockIdx.x * BN_ + wv * 16 + (lane & 15)) * ldB
                  + ((lane >> 4) * 8);

  __shared__ __align__(16) __bf16 Abuf[2][BM * BK];   // 16 KB each, XOR-swizzled

  // A staging: 4 chunks of bf16x8 per thread per K-step
  const __bf16* aptr[4];
  int aoff[4];
  #pragma unroll
  for (int i = 0; i < 4; ++i) {
    int c = tid + i * 256, r = c >> 3, s = c & 7;
    int rr = (r < rem) ? r : (rem - 1);
    int base = soff + mt0 * BM + rr;
    int arow = (EPI == 0 && ROUTED) ? tok_list[base] : base;
    aptr[i] = A + (long)arow * K + s * 8;
    aoff[i] = r * 64 + ((s ^ (r & 7)) * 8);           // swizzle: slot ^= row&7
  }

  f32x4 acc[8] = {};
  bf16x8 aR[4];
  f32x4 bA[4], bB[4];

#define LOAD_A(k) { _Pragma("unroll") \
  for (int i = 0; i < 4; ++i) aR[i] = *(const bf16x8*)(aptr[i] + (k)); }
#define STORE_A(b) { _Pragma("unroll") \
  for (int i = 0; i < 4; ++i) *(bf16x8*)&Abuf[b][aoff[i]] = aR[i]; }
#define LOAD_B(dst, k) { \
  dst[0] = *(const f32x4*)(Bp + (k));      dst[1] = *(const f32x4*)(Bp + (k) + 4); \
  dst[2] = *(const f32x4*)(Bp + (k) + 32); dst[3] = *(const f32x4*)(Bp + (k) + 36); }
#define COMPUTE(bsrc, b) { _Pragma("unroll") \
  for (int ch = 0; ch < 2; ++ch) { \
    bf16x8 bfrag = cvt8(bsrc[ch*2], bsrc[ch*2+1]); \
    const int ro = ((lane & 15) * 64) + ((((ch*4) + (lane >> 4)) ^ (lane & 7)) * 8); \
    _Pragma("unroll") \
    for (int m = 0; m < 8; ++m) { \
      bf16x8 af = *(const bf16x8*)&Abuf[b][m * 1024 + ro]; \
      acc[m] = __builtin_amdgcn_mfma_f32_16x16x32_bf16(af, bfrag, acc[m], 0, 0, 0); \
    } \
  } }

  LOAD_A(0);
  LOAD_B(bA, 0);
  const int NT = K / BK;                   // even (16 or 32) for all our shapes
  for (int t = 0; t < NT; t += 2) {
    const int k1 = (t + 1 < NT) ? (t + 1) * BK : 0;
    const int k2 = (t + 2 < NT) ? (t + 2) * BK : 0;
    STORE_A(0);
    LOAD_A(k1); LOAD_B(bB, k1);            // stay in flight across barrier+compute
    BARRIER_NODRAIN();
    COMPUTE(bA, 0);
    STORE_A(1);
    LOAD_A(k2); LOAD_B(bA, k2);
    BARRIER_NODRAIN();
    COMPUTE(bB, 1);
  }
#undef LOAD_A
#undef STORE_A
#undef LOAD_B
#undef COMPUTE

  if (EPI == 0) {
    // LDS transpose for coalesced bf16x8 stores
    __syncthreads();
    __bf16* Cs = &Abuf[0][0];
    #pragma unroll
    for (int m = 0; m < 8; ++m) {
      #pragma unroll
      for (int r = 0; r < 4; ++r) {
        int row = m * 16 + (lane >> 4) * 4 + r;
        Cs[row * 64 + wv * 16 + (lane & 15)] = (__bf16)acc[m][r];
      }
    }
    __syncthreads();
    __bf16* Cb = (__bf16*)Cout;
    #pragma unroll
    for (int p = 0; p < 4; ++p) {
      int row = p * 32 + (tid >> 3);
      if (row < rem)
        *(bf16x8*)(Cb + (long)(soff + mt0 * BM + row) * ldc + blockIdx.x * BN_ + (tid & 7) * 8) =
            *(const bf16x8*)&Cs[row * 64 + (tid & 7) * 8];
    }
  } else {
    float* Of = (float*)Cout;
    const int col = blockIdx.x * BN_ + wv * 16 + (lane & 15);
    #pragma unroll
    for (int m = 0; m < 8; ++m) {
      #pragma unroll
      for (int r = 0; r < 4; ++r) {
        int row = m * 16 + (lane >> 4) * 4 + r;
        if (row < rem) {
          if (EPI == 1) {
            int orow = tok_list[soff + mt0 * BM + row];
            atomicAdd(Of + (long)orow * HID + col, acc[m][r]);
          } else {
            Of[(long)(mt0 * BM + row) * HID + col] = acc[m][r];
          }
        }
      }
    }
  }
}

// ---------------- fuse: h = silu(g) * u * w  (in place into g) ----------------
__global__ void fuse_kernel(__bf16* __restrict__ g, const __bf16* __restrict__ u,
                            const float* __restrict__ wrow, int rshift) {
  long idx = ((long)blockIdx.x * 256 + threadIdx.x) * 8;
  bf16x8 gv = *(bf16x8*)(g + idx);
  bf16x8 uv = *(const bf16x8*)(u + idx);
  float w = wrow ? wrow[idx >> rshift] : 1.f;
  bf16x8 h;
  #pragma unroll
  for (int j = 0; j < 8; ++j) {
    float gf = (float)gv[j], uf = (float)uv[j];
    h[j] = (__bf16)(w * gf * uf / (1.f + __expf(-gf)));
  }
  *(bf16x8*)(g + idx) = h;
}

// ---------------- launch ----------------
extern "C" void kernel_launch(void* const* d_in, const int* in_sizes, int n_in,
                              void* d_out, int out_size, void* d_ws, size_t ws_size,
                              hipStream_t stream) {
  const float* x      = (const float*)d_in[0];
  const float* gate_w = (const float*)d_in[1];
  const float* e_bias = (const float*)d_in[2];
  const float* w_gate = (const float*)d_in[3];
  const float* w_up   = (const float*)d_in[4];
  const float* w_down = (const float*)d_in[5];
  const float* sw_gu  = (const float*)d_in[6];
  const float* sw_d   = (const float*)d_in[7];
  float* out = (float*)d_out;
  char* ws = (char*)d_ws;

  size_t off = 0;
  __bf16* x_bf = (__bf16*)(ws + off);        off += (size_t)T_TOK * HID * 2;   // 4 MB
  int*    ids  = (int*)(ws + off);           off += T_TOK * TOPK * 4;
  float*  wts  = (float*)(ws + off);         off += T_TOK * TOPK * 4;
  int* counts  = (int*)(ws + off);           off += 256;
  int* segoff  = (int*)(ws + off);           off += 256;
  int* cursors = (int*)(ws + off);           off += 256;
  int* pair_e  = (int*)(ws + off);           off += 1024;
  int* pair_mt = (int*)(ws + off);           off += 1024;
  int* npairs  = (int*)(ws + off);           off += 256;
  int* tok_list = (int*)(ws + off);          off += T_TOK * TOPK * 4;
  float* wgt_list = (float*)(ws + off);      off += T_TOK * TOPK * 4;
  off = (off + 255) & ~(size_t)255;
  __bf16* g_buf = (__bf16*)(ws + off);       off += (size_t)T_TOK * TOPK * IDIM * 2; // 16 MB
  __bf16* u_buf = (__bf16*)(ws + off);       off += (size_t)T_TOK * TOPK * IDIM * 2; // 16 MB
  __bf16* gs_buf = (__bf16*)(ws + off);      off += (size_t)T_TOK * ISH * 2;         // 4 MB
  __bf16* us_buf = (__bf16*)(ws + off);      off += (size_t)T_TOK * ISH * 2;         // 4 MB

  init_kernel<<<1, 64, 0, stream>>>(counts);
  xcast_kernel<<<(T_TOK * HID) / (256 * 8), 256, 0, stream>>>(x, x_bf);
  router_kernel<<<T_TOK, 256, 0, stream>>>(x, gate_w, e_bias, ids, wts, counts);
  scan_kernel<<<1, 64, 0, stream>>>(counts, segoff, cursors, pair_e, pair_mt, npairs);
  scatter_kernel<<<(T_TOK * TOPK + 255) / 256, 256, 0, stream>>>(ids, wts, cursors, tok_list, wgt_list);

  // routed gate & up (separate streams through the same kernel)
  gemm_stream<0, true><<<dim3(IDIM / BN_, 128), 256, 0, stream>>>(
      x_bf, w_gate, (long)IDIM * HID, HID, HID, g_buf, IDIM,
      pair_e, pair_mt, npairs, segoff, counts, tok_list, 0);
  gemm_stream<0, true><<<dim3(IDIM / BN_, 128), 256, 0, stream>>>(
      x_bf, w_up, (long)IDIM * HID, HID, HID, u_buf, IDIM,
      pair_e, pair_mt, npairs, segoff, counts, tok_list, 0);
  // h = silu(g)*u*w  (w includes ROUTED_SCALE and renorm)
  fuse_kernel<<<(T_TOK * TOPK * IDIM) / (256 * 8), 256, 0, stream>>>(g_buf, u_buf, wgt_list, 10);

  // shared gate & up
  gemm_stream<0, false><<<dim3(ISH / BN_, T_TOK / BM), 256, 0, stream>>>(
      x_bf, sw_gu, 0, HID, HID, gs_buf, ISH,
      nullptr, nullptr, nullptr, nullptr, nullptr, nullptr, T_TOK);
  gemm_stream<0, false><<<dim3(ISH / BN_, T_TOK / BM), 256, 0, stream>>>(
      x_bf, sw_gu + (size_t)ISH * HID, 0, HID, HID, us_buf, ISH,
      nullptr, nullptr, nullptr, nullptr, nullptr, nullptr, T_TOK);
  fuse_kernel<<<(T_TOK * ISH) / (256 * 8), 256, 0, stream>>>(gs_buf, us_buf, nullptr, 11);

  // shared down: plain stores (initializes all of d_out)
  gemm_stream<2, false><<<dim3(HID / BN_, T_TOK / BM), 256, 0, stream>>>(
      gs_buf, sw_d, 0, ISH, ISH, out, HID,
      nullptr, nullptr, nullptr, nullptr, nullptr, nullptr, T_TOK);

  // routed down: atomic accumulate (weight already folded into h)
  gemm_stream<1, true><<<dim3(HID / BN_, 128), 256, 0, stream>>>(
      g_buf, w_down, (long)HID * IDIM, IDIM, IDIM, out, HID,
      pair_e, pair_mt, npairs, segoff, counts, tok_list, 0);
}